// Round 11
// baseline (1205.084 us; speedup 1.0000x reference)
//
#include <hip/hip_runtime.h>
#include <hip/hip_bf16.h>
#include <cstdint>

#define B_ 8
#define C_ 192
#define N_ 3136
#define K_ 9
#define OC_ 384
#define QT_ 49            // q-tiles per batch (64 q each)
#define MS_ 2             // m-split over the 13 m-tiles (256 m each)
#define NT_ 13            // m-tiles (ceil(3136/256))

typedef unsigned int u32;
typedef _Float16 f16x8 __attribute__((ext_vector_type(8)));
typedef float f32x4 __attribute__((ext_vector_type(4)));

#define GLD(g, s) __builtin_amdgcn_global_load_lds( \
    (const __attribute__((address_space(1))) void*)(g), \
    (__attribute__((address_space(3))) void*)(s), 16, 0, 0)

#define WAITV2 asm volatile("s_waitcnt vmcnt(2)" ::: "memory")
#define WAITV0 asm volatile("s_waitcnt vmcnt(0)" ::: "memory")

// if-converted sorted bubble insert (static indexing, strict < keeps earlier m)
#define INS(LV, LI, dd, mm) { \
    float cv = (dd); int ci = (mm); \
    _Pragma("unroll") \
    for (int r_ = 0; r_ < 9; ++r_) { \
        bool sw_ = cv < LV[r_]; \
        float tv_ = LV[r_]; int ti_ = LI[r_]; \
        LV[r_] = sw_ ? cv : tv_;  LI[r_] = sw_ ? ci : ti_; \
        cv = sw_ ? tv_ : cv;      ci = sw_ ? ti_ : ci; \
    } }

// ---------------- Kernel A: normalize + f16 hi/lo split + transpose + sq ----------------
__global__ __launch_bounds__(256) void prep_k(const float* __restrict__ x,
                                              _Float16* __restrict__ pHL,
                                              float* __restrict__ xT,
                                              float* __restrict__ sq) {
    int g = blockIdx.x * 256 + threadIdx.x;      // 98*256 = 25088 exact
    int b = g / N_, n = g % N_;
    const float* xb = x + (size_t)b * C_ * N_ + n;
    float ss = 0.f;
    for (int c = 0; c < C_; ++c) { float v = xb[(size_t)c * N_]; ss = fmaf(v, v, ss); }
    float den = fmaxf(sqrtf(ss), 1e-12f);
    float* xrow = xT + (size_t)g * C_;
    _Float16* hrow = pHL + (size_t)g * 384;
    float s2 = 0.f;
    for (int c4 = 0; c4 < 48; ++c4) {
        float4 vv; float* pv = &vv.x;
        union { _Float16 f[4]; uint2 u; } uh, ul;
        #pragma unroll
        for (int j = 0; j < 4; ++j) {
            int c = 4 * c4 + j;
            float v = xb[(size_t)c * N_];
            float p = v / den;                    // IEEE div, matches np divide
            pv[j] = v;
            _Float16 h = (_Float16)p;            // rne
            uh.f[j] = h;
            ul.f[j] = (_Float16)(p - (float)h);  // residual
            s2 = fmaf(p, p, s2);                 // sq chain identical to passing rounds
        }
        *(float4*)&xrow[4 * c4] = vv;
        *(uint2*)&hrow[4 * c4] = uh.u;
        *(uint2*)&hrow[192 + 4 * c4] = ul.u;
    }
    sq[g] = s2;
}

// ---------------- Kernel B: MFMA distance GEMM, 16 waves/CU, barrier-free K-loop ----
// Block 64q x 256m, 1024 threads (4 waves/SIMD). Q resident 48KB; M dbuf 2x32KB
// wave-local (rows [16w,16w+16), 2 GLD/kc, counted WAITV2 -> no barriers in kc-loop).
__global__ __launch_bounds__(1024, 4) void knn_k(const _Float16* __restrict__ pHL,
                                                 const float* __restrict__ sq,
                                                 float* __restrict__ pkv,
                                                 int* __restrict__ pki) {
    __shared__ _Float16 sh[57344];                // 112KB: Q 0..24575 | M0 24576 | M1 40960
    float* dist = (float*)(sh + 40960);           // 32KB, aliases M1 (dead at epilogue)
    const int tid = threadIdx.x;
    const int w = tid >> 6, l = tid & 63;         // w 0..15
    const int lr = l & 15, lg = l >> 4;
    const int bid = blockIdx.x;
    const int b = bid & 7;                        // XCD-affinity: one batch per XCD
    const int r2_ = bid >> 3;                     // 0..97
    const int qt = r2_ >> 1, s4 = r2_ & 1;
    const int q0 = qt * 64;
    const char* hbB = (const char*)(pHL + (size_t)b * N_ * 384);
    const float* sqb = sq + b * N_;

    // swizzled per-lane source (LDS[node][slot s] = global octet s^(node&7))
    const int nl = l >> 3, sl = l & 7, ol = sl ^ nl;
    const size_t lane_src = (size_t)nl * 768 + (size_t)(ol >> 2) * 384 + (size_t)(ol & 3) * 16;
    const int slot_h = (lg ^ (lr & 7)) * 8;
    const int slot_l = ((4 | lg) ^ (lr & 7)) * 8;

    float sqq[4][4];
    #pragma unroll
    for (int qs = 0; qs < 4; ++qs)
        #pragma unroll
        for (int r = 0; r < 4; ++r) sqq[qs][r] = sqb[q0 + 16 * qs + 4 * lg + r];

    float lv[9]; int li[9];
    #pragma unroll
    for (int r = 0; r < 9; ++r) { lv[r] = INFINITY; li[r] = 0x7fffffff; }

    auto stageM = [&](int mt_, int kc_, int buf) { // wave-local rows [16w,16w+16)
        size_t mb = (size_t)(mt_ * 256 + w * 16) * 768 + (size_t)kc_ * 64;
        _Float16* md = sh + 24576 + buf * 16384 + w * 1024;
        GLD(hbB + mb + lane_src, md);
        GLD(hbB + mb + 6144 + lane_src, md + 512);
    };

    // ---- stage Q once: 48 x 1KB GLD, 3 per wave ----
    #pragma unroll
    for (int i = 0; i < 3; ++i) {
        int idx = w * 3 + i;                      // 0..47
        int kcq = idx >> 3, grp = idx & 7;
        size_t qb = (size_t)(q0 + 8 * grp) * 768 + (size_t)kcq * 64;
        GLD(hbB + qb + lane_src, sh + kcq * 4096 + grp * 512);
    }
    __syncthreads();                              // Q visible (drains vmem)
    stageM(s4, 0, 0);                             // prologue: M kc0 -> buf0 (2 outstanding)

    for (int mt = s4; mt < NT_; mt += MS_) {
        const int m0 = mt * 256;
        f32x4 acc[4];
        #pragma unroll
        for (int qs = 0; qs < 4; ++qs) acc[qs] = (f32x4)0.f;

        #pragma unroll
        for (int kc = 0; kc < 6; ++kc) {          // NO barriers in this loop
            const int nmt = (kc < 5) ? mt : mt + MS_;
            const int nkc = (kc < 5) ? kc + 1 : 0;
            if (nmt < NT_) {
                stageM(nmt, nkc, (kc + 1) & 1);   // issue next (incl. cross-tile kc0)
                WAITV2;                           // oldest 2 = stage(kc) complete
            } else {
                WAITV0;
            }
            const _Float16* Qb = sh + kc * 4096;
            const _Float16* mrow = sh + 24576 + (kc & 1) * 16384 + (16 * w + lr) * 64;
            f16x8 bh = *(const f16x8*)(mrow + slot_h);
            f16x8 bl = *(const f16x8*)(mrow + slot_l);
            #pragma unroll
            for (int qs = 0; qs < 4; ++qs) {
                const _Float16* qrow = Qb + (16 * qs + lr) * 64;
                f16x8 ah = *(const f16x8*)(qrow + slot_h);
                f16x8 al = *(const f16x8*)(qrow + slot_l);
                acc[qs] = __builtin_amdgcn_mfma_f32_16x16x32_f16(al, bh, acc[qs], 0, 0, 0);
                acc[qs] = __builtin_amdgcn_mfma_f32_16x16x32_f16(ah, bl, acc[qs], 0, 0, 0);
                acc[qs] = __builtin_amdgcn_mfma_f32_16x16x32_f16(ah, bh, acc[qs], 0, 0, 0);
            }
        }
        __syncthreads();                          // all reads of M1 done -> dist may alias

        float sqm;
        { int m = m0 + 16 * w + lr; sqm = (m < N_) ? sqb[m] : 0.f; }

        #pragma unroll
        for (int pm = 0; pm < 2; ++pm) {          // dist[128 cols][64 q] phases
            if (m0 + 128 * pm >= N_) break;       // block-uniform tail skip
            if ((w >> 3) == pm) {                 // writer waves 8pm..8pm+7
                int col = 16 * (w & 7) + lr;
                #pragma unroll
                for (int qs = 0; qs < 4; ++qs) {
                    int gsw = ((4 * qs + lg) ^ lr) << 2;   // XOR-granule swizzle
                    float4 v;
                    v.x = (sqq[qs][0] - 2.0f * acc[qs][0]) + sqm;
                    v.y = (sqq[qs][1] - 2.0f * acc[qs][1]) + sqm;
                    v.z = (sqq[qs][2] - 2.0f * acc[qs][2]) + sqm;
                    v.w = (sqq[qs][3] - 2.0f * acc[qs][3]) + sqm;
                    *(float4*)&dist[col * 64 + gsw] = v;
                }
            }
            __syncthreads();
            // scan: query = l; thread covers cols {16*jj + w}; col&15 == w
            const int gq = l >> 2, qe = l & 3;
            #pragma unroll
            for (int jj = 0; jj < 8; ++jj) {
                int col = 16 * jj + w;
                int m = m0 + 128 * pm + col;
                if (m < N_) {                     // wave-uniform branch
                    float d = dist[col * 64 + ((gq ^ w) << 2) + qe];
                    INS(lv, li, d, m)
                }
            }
            __syncthreads();                      // scans done before dist overwritten
        }
    }
    // ---- merge the 16 lists per query (stable: val asc, idx asc) ----
    float* Lv = (float*)sh;                       // 36 KB
    int*   Li = (int*)sh + 9216;                  // next 36 KB (Q/M0 dead)
    #pragma unroll
    for (int r = 0; r < 9; ++r) { Lv[tid * 9 + r] = lv[r]; Li[tid * 9 + r] = li[r]; }
    __syncthreads();
    if (tid < 64) {
        size_t base = ((size_t)((b * QT_ + qt) * MS_ + s4) * 64 + tid) * 9;
        for (int r = 0; r < K_; ++r) {
            float best = INFINITY; int bidx = 0x7fffffff; int bp = 0;
            for (int s = 0; s < 16; ++s) {
                int lb = (s * 64 + tid) * 9;
                for (int e = 0; e < 9; ++e) {
                    float v = Lv[lb + e]; int id = Li[lb + e];
                    if (v < best || (v == best && id < bidx)) { best = v; bidx = id; bp = lb + e; }
                }
            }
            pkv[base + r] = best;
            pki[base + r] = bidx;
            Lv[bp] = INFINITY;
        }
    }
}

// ---------------- Kernel B2: merge the 2 stride lists per query ----------------
__global__ __launch_bounds__(256) void merge_k(const float* __restrict__ pkv,
                                               const int* __restrict__ pki,
                                               int* __restrict__ nn) {
    int g = blockIdx.x * 256 + threadIdx.x;       // 98*256 = 25088 exact
    int b = g / N_, n = g % N_;
    int qt = n >> 6, q = n & 63;
    float v[MS_ * 9]; int id[MS_ * 9];
    #pragma unroll
    for (int s = 0; s < MS_; ++s) {
        size_t base = ((size_t)((b * QT_ + qt) * MS_ + s) * 64 + q) * 9;
        #pragma unroll
        for (int e = 0; e < 9; ++e) { v[s * 9 + e] = pkv[base + e]; id[s * 9 + e] = pki[base + e]; }
    }
    int* onn = nn + (size_t)g * K_;
    for (int r = 0; r < K_; ++r) {
        float best = INFINITY; int bidx = 0x7fffffff; int bp = 0;
        #pragma unroll
        for (int e = 0; e < MS_ * 9; ++e) {
            if (v[e] < best || (v[e] == best && id[e] < bidx)) { best = v[e]; bidx = id[e]; bp = e; }
        }
        onn[r] = bidx;
        v[bp] = INFINITY;
    }
}

// ---------------- Kernel C: channels 0..191 (x_i only -> k-independent) ----------------
__global__ __launch_bounds__(256) void convi_k(const float* __restrict__ x,
                                               const float* __restrict__ W,
                                               const float* __restrict__ bias,
                                               float* __restrict__ out) {
    __shared__ float Ws[48 * 96];
    const int orange = blockIdx.x & 3;
    const int nb = blockIdx.x >> 2;
    const int tid = threadIdx.x;
    const int g = nb * 256 + tid;
    const int b = g / N_, n = g % N_;
    const int o0 = orange * 48;
    const int cb = (o0 >= 96) ? 96 : 0;
    for (int i = 0; i < 18; ++i) {
        int e = tid + i * 256;
        Ws[e] = W[o0 * 96 + e];
    }
    __syncthreads();
    const float* xb = x + ((size_t)b * C_ + cb) * N_ + n;
    float xi[96];
    #pragma unroll
    for (int c = 0; c < 96; ++c) xi[c] = xb[(size_t)c * N_];
    float* ob = out + ((size_t)b * OC_ + o0) * N_ + n;
    for (int o = 0; o < 48; ++o) {
        float a = bias[o0 + o];
        #pragma unroll
        for (int c4 = 0; c4 < 24; ++c4) {
            float4 w4 = *(const float4*)&Ws[o * 96 + 4 * c4];
            a = fmaf(w4.x, xi[4*c4+0], a);
            a = fmaf(w4.y, xi[4*c4+1], a);
            a = fmaf(w4.z, xi[4*c4+2], a);
            a = fmaf(w4.w, xi[4*c4+3], a);
        }
        ob[(size_t)o * N_] = fmaxf(a, 0.f);
    }
}

// ---------------- Kernel D: channels 192..383 (x_j - x_i, max over k) ----------------
__device__ __forceinline__ float blo(u32 u) { return __uint_as_float(u << 16); }
__device__ __forceinline__ float bhi(u32 u) { return __uint_as_float(u & 0xffff0000u); }

__device__ __forceinline__ void rd9(float* d, const __hip_bfloat16* base, int c) {
    const u32* p = (const u32*)(base + c * 12);
    u32 u0 = p[0], u1 = p[1], u2 = p[2], u3 = p[3], u4 = p[4];
    d[0] = blo(u0); d[1] = bhi(u0); d[2] = blo(u1); d[3] = bhi(u1);
    d[4] = blo(u2); d[5] = bhi(u2); d[6] = blo(u3); d[7] = bhi(u3); d[8] = blo(u4);
}

__global__ __launch_bounds__(256) void convd_k(const float* __restrict__ xT,
                                               const int* __restrict__ nn,
                                               const float* __restrict__ W,
                                               const float* __restrict__ bias,
                                               float* __restrict__ out) {
    __shared__ __hip_bfloat16 Wb[192 * 104];
    __shared__ __hip_bfloat16 dif[4][192 * 12];
    const int tid = threadIdx.x;
    const int w = tid >> 6, l = tid & 63;
    const int b = blockIdx.x / 196;
    const int n0 = (blockIdx.x % 196) * 16;

    for (int i = 0; i < 72; ++i) {
        int e = tid + i * 256;
        int row = e / 96, j = e % 96;
        Wb[row * 104 + j] = __float2bfloat16(W[(192 + row) * 96 + j]);
    }
    float bo[3];
    #pragma unroll
    for (int oi = 0; oi < 3; ++oi) bo[oi] = bias[192 + l + 64 * oi];
    __syncthreads();

    __hip_bfloat16* df = dif[w];
    const float* xTb = xT + (size_t)b * N_ * C_;
    float mx0[4], mx1[4], mx2[4];

    #pragma unroll
    for (int r = 0; r < 4; ++r) {
        const int n = n0 + 4 * w + r;
        const float* xin = xTb + (size_t)n * C_;
        float xi0 = xin[l], xi1 = xin[l + 64], xi2 = xin[l + 128];
        const int* nb2 = nn + ((size_t)b * N_ + n) * K_;
        __syncthreads();
        #pragma unroll
        for (int k = 0; k < K_; ++k) {
            int idx = nb2[k];
            const float* xj = xTb + (size_t)idx * C_;
            df[(l)      * 12 + k] = __float2bfloat16(xj[l]       - xi0);
            df[(l + 64) * 12 + k] = __float2bfloat16(xj[l + 64]  - xi1);
            df[(l + 128)* 12 + k] = __float2bfloat16(xj[l + 128] - xi2);
        }
        __syncthreads();
        float a0[9], a1[9], a2[9];
        #pragma unroll
        for (int k = 0; k < 9; ++k) { a0[k] = 0.f; a1[k] = 0.f; a2[k] = 0.f; }

        for (int jj = 0; jj < 12; ++jj) {
            float w0[8], w1[8], w2[8];
            {
                uint4 rw = *(const uint4*)(Wb + (size_t)(l)       * 104 + jj * 8);
                w0[0]=blo(rw.x); w0[1]=bhi(rw.x); w0[2]=blo(rw.y); w0[3]=bhi(rw.y);
                w0[4]=blo(rw.z); w0[5]=bhi(rw.z); w0[6]=blo(rw.w); w0[7]=bhi(rw.w);
            }
            {
                uint4 rw = *(const uint4*)(Wb + (size_t)(l + 64)  * 104 + jj * 8);
                w1[0]=blo(rw.x); w1[1]=bhi(rw.x); w1[2]=blo(rw.y); w1[3]=bhi(rw.y);
                w1[4]=blo(rw.z); w1[5]=bhi(rw.z); w1[6]=blo(rw.w); w1[7]=bhi(rw.w);
            }
            {
                uint4 rw = *(const uint4*)(Wb + (size_t)(l + 128) * 104 + jj * 8);
                w2[0]=blo(rw.x); w2[1]=bhi(rw.x); w2[2]=blo(rw.y); w2[3]=bhi(rw.y);
                w2[4]=blo(rw.z); w2[5]=bhi(rw.z); w2[6]=blo(rw.w); w2[7]=bhi(rw.w);
            }
            #pragma unroll
            for (int jr = 0; jr < 8; ++jr) {
                int j = jj * 8 + jr;
                int c0r = j;
                int c2r = 96 + j;
                int c1r = (l >= 32) ? c2r : c0r;
                float d0[9], d1[9], d2[9];
                rd9(d0, df, c0r); rd9(d1, df, c1r); rd9(d2, df, c2r);
                #pragma unroll
                for (int k = 0; k < 9; ++k) {
                    a0[k] = fmaf(w0[jr], d0[k], a0[k]);
                    a1[k] = fmaf(w1[jr], d1[k], a1[k]);
                    a2[k] = fmaf(w2[jr], d2[k], a2[k]);
                }
            }
        }
        float m0 = a0[0] + bo[0], m1 = a1[0] + bo[1], m2 = a2[0] + bo[2];
        #pragma unroll
        for (int k = 1; k < 9; ++k) {
            m0 = fmaxf(m0, a0[k] + bo[0]);
            m1 = fmaxf(m1, a1[k] + bo[1]);
            m2 = fmaxf(m2, a2[k] + bo[2]);
        }
        mx0[r] = fmaxf(m0, 0.f); mx1[r] = fmaxf(m1, 0.f); mx2[r] = fmaxf(m2, 0.f);
    }
    float* ob = out + ((size_t)b * OC_ + 192) * N_ + n0 + 4 * w;
    *(float4*)&ob[(size_t)(l)       * N_] = make_float4(mx0[0], mx0[1], mx0[2], mx0[3]);
    *(float4*)&ob[(size_t)(l + 64)  * N_] = make_float4(mx1[0], mx1[1], mx1[2], mx1[3]);
    *(float4*)&ob[(size_t)(l + 128) * N_] = make_float4(mx2[0], mx2[1], mx2[2], mx2[3]);
}

extern "C" void kernel_launch(void* const* d_in, const int* in_sizes, int n_in,
                              void* d_out, int out_size, void* d_ws, size_t ws_size,
                              hipStream_t stream) {
    (void)in_sizes; (void)n_in; (void)out_size; (void)ws_size;
    const float* x    = (const float*)d_in[0];
    const float* W    = (const float*)d_in[1];
    const float* bias = (const float*)d_in[2];
    float* out = (float*)d_out;

    _Float16* pHL = (_Float16*)d_ws;                       // 8*3136*384 f16 (hi|lo, node-major)
    float* xT   = (float*)(pHL + (size_t)B_ * N_ * 384);   // 8*3136*192 f32 raw
    float* sq   = xT + (size_t)B_ * N_ * C_;               // 8*3136 f32
    int*   nn   = (int*)(sq + (size_t)B_ * N_);            // 8*3136*9 i32
    float* pkv  = (float*)(nn + (size_t)B_ * N_ * K_);     // partial vals
    int*   pki  = (int*)(pkv + (size_t)B_ * QT_ * MS_ * 64 * 9);

    hipLaunchKernelGGL(prep_k,  dim3(98),   dim3(256), 0, stream, x, pHL, xT, sq);
    hipLaunchKernelGGL(knn_k,   dim3(B_ * QT_ * MS_), dim3(1024), 0, stream, pHL, sq, pkv, pki);
    hipLaunchKernelGGL(merge_k, dim3(98),   dim3(256), 0, stream, pkv, pki, nn);
    hipLaunchKernelGGL(convi_k, dim3(392),  dim3(256), 0, stream, x, W, bias, out);
    hipLaunchKernelGGL(convd_k, dim3(1568), dim3(256), 0, stream, xT, nn, W, bias, out);
}

// Round 12
// 998.408 us; speedup vs baseline: 1.2070x; 1.2070x over previous
//
#include <hip/hip_runtime.h>
#include <hip/hip_bf16.h>
#include <cstdint>

#define B_ 8
#define C_ 192
#define N_ 3136
#define K_ 9
#define OC_ 384
#define QT_ 49            // q-tiles per batch (64 q each)
#define MS_ 4             // m-split over the 25 m-tiles (128 m each)
#define NT_ 25            // m-tiles
#define QSZ 24576         // Q region: 6 kc x 64 node x 64 f16 = 48KB

typedef unsigned int u32;
typedef _Float16 f16x8 __attribute__((ext_vector_type(8)));
typedef float f32x4 __attribute__((ext_vector_type(4)));

#define GLD(g, s) __builtin_amdgcn_global_load_lds( \
    (const __attribute__((address_space(1))) void*)(g), \
    (__attribute__((address_space(3))) void*)(s), 16, 0, 0)

#define WAITV4 asm volatile("s_waitcnt vmcnt(4)" ::: "memory")
#define WAITV0 asm volatile("s_waitcnt vmcnt(0)" ::: "memory")

// if-converted sorted bubble insert (static indexing, strict < keeps earlier m)
#define INS(LV, LI, dd, mm) { \
    float cv = (dd); int ci = (mm); \
    _Pragma("unroll") \
    for (int r_ = 0; r_ < 9; ++r_) { \
        bool sw_ = cv < LV[r_]; \
        float tv_ = LV[r_]; int ti_ = LI[r_]; \
        LV[r_] = sw_ ? cv : tv_;  LI[r_] = sw_ ? ci : ti_; \
        cv = sw_ ? tv_ : cv;      ci = sw_ ? ti_ : ci; \
    } }

// ---------------- Kernel A: normalize + f16 hi/lo split + transpose + sq ----------------
__global__ __launch_bounds__(256) void prep_k(const float* __restrict__ x,
                                              _Float16* __restrict__ pHL,
                                              float* __restrict__ xT,
                                              float* __restrict__ sq) {
    int g = blockIdx.x * 256 + threadIdx.x;      // 98*256 = 25088 exact
    int b = g / N_, n = g % N_;
    const float* xb = x + (size_t)b * C_ * N_ + n;
    float ss = 0.f;
    for (int c = 0; c < C_; ++c) { float v = xb[(size_t)c * N_]; ss = fmaf(v, v, ss); }
    float den = fmaxf(sqrtf(ss), 1e-12f);
    float* xrow = xT + (size_t)g * C_;
    _Float16* hrow = pHL + (size_t)g * 384;
    float s2 = 0.f;
    for (int c4 = 0; c4 < 48; ++c4) {
        float4 vv; float* pv = &vv.x;
        union { _Float16 f[4]; uint2 u; } uh, ul;
        #pragma unroll
        for (int j = 0; j < 4; ++j) {
            int c = 4 * c4 + j;
            float v = xb[(size_t)c * N_];
            float p = v / den;                    // IEEE div, matches np divide
            pv[j] = v;
            _Float16 h = (_Float16)p;            // rne
            uh.f[j] = h;
            ul.f[j] = (_Float16)(p - (float)h);  // residual
            s2 = fmaf(p, p, s2);                 // sq chain identical to passing rounds
        }
        *(float4*)&xrow[4 * c4] = vv;
        *(uint2*)&hrow[4 * c4] = uh.u;
        *(uint2*)&hrow[192 + 4 * c4] = ul.u;
    }
    sq[g] = s2;
}

// ---------------- Kernel B: MFMA distance GEMM (R10, verbatim) ----------------
__global__ __launch_bounds__(256, 2) void knn_k(const _Float16* __restrict__ pHL,
                                                const float* __restrict__ sq,
                                                float* __restrict__ pkv,
                                                int* __restrict__ pki) {
    __shared__ _Float16 sh[40960];                // Q: 0..24575 | M0: +0 | M1: +8192
    float* dist = (float*)(sh + QSZ + 8192);      // aliases M1 (kc5 buf, dead at epilogue)
    const int tid = threadIdx.x;
    const int w = tid >> 6, l = tid & 63;
    const int lr = l & 15, lg = l >> 4;
    const int bid = blockIdx.x;
    const int b = bid & 7;                        // XCD-affinity: one batch per XCD
    const int r2_ = bid >> 3;                     // 0..195
    const int qt = r2_ >> 2, s4 = r2_ & 3;
    const int q0 = qt * 64;
    const char* hbB = (const char*)(pHL + (size_t)b * N_ * 384);
    const float* sqb = sq + b * N_;

    const int nl = l >> 3, sl = l & 7, ol = sl ^ nl;
    const size_t lane_src = (size_t)nl * 768 + (size_t)(ol >> 2) * 384 + (size_t)(ol & 3) * 16;
    const int slot_h = (lg ^ (lr & 7)) * 8;
    const int slot_l = ((4 | lg) ^ (lr & 7)) * 8;

    float sqq[4][4];
    #pragma unroll
    for (int qs = 0; qs < 4; ++qs)
        #pragma unroll
        for (int r = 0; r < 4; ++r) sqq[qs][r] = sqb[q0 + 16 * qs + 4 * lg + r];

    float lvA[9], lvB[9]; int liA[9], liB[9];
    #pragma unroll
    for (int r = 0; r < 9; ++r) {
        lvA[r] = INFINITY; liA[r] = 0x7fffffff;
        lvB[r] = INFINITY; liB[r] = 0x7fffffff;
    }

    auto stageM = [&](int mt_, int kc_, int buf) { // wave-local rows [32w, 32w+32)
        size_t mb = (size_t)(mt_ * 128 + w * 32) * 768 + (size_t)kc_ * 64;
        _Float16* md = sh + QSZ + buf * 8192 + w * 2048;
        #pragma unroll
        for (int i = 0; i < 4; ++i)
            GLD(hbB + mb + (size_t)i * 6144 + lane_src, md + i * 512);
    };

    #pragma unroll
    for (int kc = 0; kc < 6; ++kc) {
        size_t qb = (size_t)(q0 + w * 16) * 768 + (size_t)kc * 64;
        _Float16* qd = sh + kc * 4096 + w * 1024;
        GLD(hbB + qb + lane_src, qd);
        GLD(hbB + qb + 6144 + lane_src, qd + 512);
    }
    __syncthreads();                              // Q visible (drains vmem)
    stageM(s4, 0, 0);

    for (int mt = s4; mt < NT_; mt += MS_) {
        const int m0 = mt * 128;
        f32x4 acc[4][2];
        #pragma unroll
        for (int qs = 0; qs < 4; ++qs)
            #pragma unroll
            for (int ms = 0; ms < 2; ++ms) acc[qs][ms] = (f32x4)0.f;

        #pragma unroll
        for (int kc = 0; kc < 6; ++kc) {          // NO barriers in this loop
            const int nmt = (kc < 5) ? mt : mt + MS_;
            const int nkc = (kc < 5) ? kc + 1 : 0;
            if (nmt < NT_) {
                stageM(nmt, nkc, (kc + 1) & 1);
                WAITV4;
            } else {
                WAITV0;
            }
            const _Float16* Qb = sh + kc * 4096;
            const _Float16* Mb = sh + QSZ + (kc & 1) * 8192;
            f16x8 ah[4], al[4];
            #pragma unroll
            for (int qs = 0; qs < 4; ++qs) {
                const _Float16* qrow = Qb + (16 * qs + lr) * 64;
                ah[qs] = *(const f16x8*)(qrow + slot_h);
                al[qs] = *(const f16x8*)(qrow + slot_l);
            }
            #pragma unroll
            for (int ms = 0; ms < 2; ++ms) {
                const _Float16* mrow = Mb + (32 * w + 16 * ms + lr) * 64;
                f16x8 bh = *(const f16x8*)(mrow + slot_h);
                f16x8 bl = *(const f16x8*)(mrow + slot_l);
                #pragma unroll
                for (int qs = 0; qs < 4; ++qs) {
                    acc[qs][ms] = __builtin_amdgcn_mfma_f32_16x16x32_f16(al[qs], bh, acc[qs][ms], 0, 0, 0);
                    acc[qs][ms] = __builtin_amdgcn_mfma_f32_16x16x32_f16(ah[qs], bl, acc[qs][ms], 0, 0, 0);
                    acc[qs][ms] = __builtin_amdgcn_mfma_f32_16x16x32_f16(ah[qs], bh, acc[qs][ms], 0, 0, 0);
                }
            }
        }
        __syncthreads();                          // all waves done reading M bufs

        float sqm[2];
        #pragma unroll
        for (int ms = 0; ms < 2; ++ms) {
            int m = m0 + 32 * w + 16 * ms + lr;
            sqm[ms] = (m < N_) ? sqb[m] : 0.f;
        }
        #pragma unroll
        for (int pm = 0; pm < 2; ++pm) {
            if (m0 + 64 * pm >= N_) break;
            if ((w >> 1) == pm) {
                #pragma unroll
                for (int qs = 0; qs < 4; ++qs)
                    #pragma unroll
                    for (int ms = 0; ms < 2; ++ms) {
                        int col = 32 * (w & 1) + 16 * ms + lr;
                        int gsw = ((4 * qs + lg) ^ lr) << 2;
                        float4 v;
                        v.x = (sqq[qs][0] - 2.0f * acc[qs][ms][0]) + sqm[ms];
                        v.y = (sqq[qs][1] - 2.0f * acc[qs][ms][1]) + sqm[ms];
                        v.z = (sqq[qs][2] - 2.0f * acc[qs][ms][2]) + sqm[ms];
                        v.w = (sqq[qs][3] - 2.0f * acc[qs][ms][3]) + sqm[ms];
                        *(float4*)&dist[col * 64 + gsw] = v;
                    }
            }
            __syncthreads();
            const int gq = l >> 2, qe = l & 3;
            #pragma unroll
            for (int jj = 0; jj < 16; ++jj) {
                int col = 16 * w + jj;
                int m = m0 + 64 * pm + col;
                if (m < N_) {
                    float d = dist[col * 64 + ((gq ^ (col & 15)) << 2) + qe];
                    if (jj & 1) { INS(lvB, liB, d, m) }
                    else        { INS(lvA, liA, d, m) }
                }
            }
            __syncthreads();
        }
    }
    float* Lv = (float*)sh;
    int*   Li = (int*)sh + 4608;
    #pragma unroll
    for (int r = 0; r < 9; ++r) {
        Lv[(tid * 2 + 0) * 9 + r] = lvA[r]; Li[(tid * 2 + 0) * 9 + r] = liA[r];
        Lv[(tid * 2 + 1) * 9 + r] = lvB[r]; Li[(tid * 2 + 1) * 9 + r] = liB[r];
    }
    __syncthreads();
    if (tid < 64) {
        size_t base = ((size_t)((b * QT_ + qt) * MS_ + s4) * 64 + tid) * 9;
        for (int r = 0; r < K_; ++r) {
            float best = INFINITY; int bidx = 0x7fffffff; int bp = 0;
            for (int s = 0; s < 8; ++s) {
                int lb = (((s >> 1) * 64 + tid) * 2 + (s & 1)) * 9;
                for (int e = 0; e < 9; ++e) {
                    float v = Lv[lb + e]; int id = Li[lb + e];
                    if (v < best || (v == best && id < bidx)) { best = v; bidx = id; bp = lb + e; }
                }
            }
            pkv[base + r] = best;
            pki[base + r] = bidx;
            Lv[bp] = INFINITY;
        }
    }
}

// ---------------- Kernel B2: merge the 4 stride lists per query ----------------
__global__ __launch_bounds__(256) void merge_k(const float* __restrict__ pkv,
                                               const int* __restrict__ pki,
                                               int* __restrict__ nn) {
    int g = blockIdx.x * 256 + threadIdx.x;       // 98*256 = 25088 exact
    int b = g / N_, n = g % N_;
    int qt = n >> 6, q = n & 63;
    float v[MS_ * 9]; int id[MS_ * 9];
    #pragma unroll
    for (int s = 0; s < MS_; ++s) {
        size_t base = ((size_t)((b * QT_ + qt) * MS_ + s) * 64 + q) * 9;
        #pragma unroll
        for (int e = 0; e < 9; ++e) { v[s * 9 + e] = pkv[base + e]; id[s * 9 + e] = pki[base + e]; }
    }
    int* onn = nn + (size_t)g * K_;
    for (int r = 0; r < K_; ++r) {
        float best = INFINITY; int bidx = 0x7fffffff; int bp = 0;
        #pragma unroll
        for (int e = 0; e < MS_ * 9; ++e) {
            if (v[e] < best || (v[e] == best && id[e] < bidx)) { best = v[e]; bidx = id[e]; bp = e; }
        }
        onn[r] = bidx;
        v[bp] = INFINITY;
    }
}

// ---------------- Kernel C: channels 0..191 (x_i only -> k-independent) ----------------
__global__ __launch_bounds__(256) void convi_k(const float* __restrict__ x,
                                               const float* __restrict__ W,
                                               const float* __restrict__ bias,
                                               float* __restrict__ out) {
    __shared__ float Ws[48 * 96];
    const int orange = blockIdx.x & 3;
    const int nb = blockIdx.x >> 2;
    const int tid = threadIdx.x;
    const int g = nb * 256 + tid;
    const int b = g / N_, n = g % N_;
    const int o0 = orange * 48;
    const int cb = (o0 >= 96) ? 96 : 0;
    for (int i = 0; i < 18; ++i) {
        int e = tid + i * 256;
        Ws[e] = W[o0 * 96 + e];
    }
    __syncthreads();
    const float* xb = x + ((size_t)b * C_ + cb) * N_ + n;
    float xi[96];
    #pragma unroll
    for (int c = 0; c < 96; ++c) xi[c] = xb[(size_t)c * N_];
    float* ob = out + ((size_t)b * OC_ + o0) * N_ + n;
    for (int o = 0; o < 48; ++o) {
        float a = bias[o0 + o];
        #pragma unroll
        for (int c4 = 0; c4 < 24; ++c4) {
            float4 w4 = *(const float4*)&Ws[o * 96 + 4 * c4];
            a = fmaf(w4.x, xi[4*c4+0], a);
            a = fmaf(w4.y, xi[4*c4+1], a);
            a = fmaf(w4.z, xi[4*c4+2], a);
            a = fmaf(w4.w, xi[4*c4+3], a);
        }
        ob[(size_t)o * N_] = fmaxf(a, 0.f);
    }
}

// ---------------- Kernel D: channels 192..383 (x_j - x_i, max over k) ----------------
// dif transposed to [k][c]: d-operand reads become 2 broadcast ds_read_b128
// per (jj,k); a1's group select is a register cndmask. Wb stride 106 (53 words,
// gcd 1 -> conflict-free). FMA order per (o,k) unchanged (j ascending).
__device__ __forceinline__ float blo(u32 u) { return __uint_as_float(u << 16); }
__device__ __forceinline__ float bhi(u32 u) { return __uint_as_float(u & 0xffff0000u); }

__global__ __launch_bounds__(256) void convd_k(const float* __restrict__ xT,
                                               const int* __restrict__ nn,
                                               const float* __restrict__ W,
                                               const float* __restrict__ bias,
                                               float* __restrict__ out) {
    __shared__ __hip_bfloat16 Wb[192 * 106];      // 40704 B
    __shared__ __hip_bfloat16 dif[4][9 * 192];    // [wave][k][c], 13824 B
    const int tid = threadIdx.x;
    const int w = tid >> 6, l = tid & 63;
    const int b = blockIdx.x / 196;
    const int n0 = (blockIdx.x % 196) * 16;
    const bool hi2 = (l >= 32);                   // a1 group select

    for (int i = 0; i < 72; ++i) {
        int e = tid + i * 256;                    // 18432 = 192*96
        int row = e / 96, j = e % 96;
        Wb[row * 106 + j] = __float2bfloat16(W[(192 + row) * 96 + j]);
    }
    float bo[3];
    #pragma unroll
    for (int oi = 0; oi < 3; ++oi) bo[oi] = bias[192 + l + 64 * oi];
    __syncthreads();

    __hip_bfloat16* df = dif[w];
    const float* xTb = xT + (size_t)b * N_ * C_;
    float mx0[4], mx1[4], mx2[4];

    #pragma unroll
    for (int r = 0; r < 4; ++r) {
        const int n = n0 + 4 * w + r;
        const float* xin = xTb + (size_t)n * C_;
        float xi0 = xin[l], xi1 = xin[l + 64], xi2 = xin[l + 128];
        const int* nb2 = nn + ((size_t)b * N_ + n) * K_;
        __syncthreads();                          // WAR vs previous round's reads
        #pragma unroll
        for (int k = 0; k < K_; ++k) {
            int idx = nb2[k];
            const float* xj = xTb + (size_t)idx * C_;
            df[k * 192 + l]       = __float2bfloat16(xj[l]       - xi0);
            df[k * 192 + l + 64]  = __float2bfloat16(xj[l + 64]  - xi1);
            df[k * 192 + l + 128] = __float2bfloat16(xj[l + 128] - xi2);
        }
        __syncthreads();                          // writes visible
        float a0[9], a1[9], a2[9];
        #pragma unroll
        for (int k = 0; k < 9; ++k) { a0[k] = 0.f; a1[k] = 0.f; a2[k] = 0.f; }

        for (int jj = 0; jj < 12; ++jj) {
            float w0[8], w1[8], w2[8];
            {
                uint4 rw = *(const uint4*)(Wb + (size_t)l * 106 + jj * 8);
                w0[0]=blo(rw.x); w0[1]=bhi(rw.x); w0[2]=blo(rw.y); w0[3]=bhi(rw.y);
                w0[4]=blo(rw.z); w0[5]=bhi(rw.z); w0[6]=blo(rw.w); w0[7]=bhi(rw.w);
            }
            {
                uint4 rw = *(const uint4*)(Wb + (size_t)(l + 64) * 106 + jj * 8);
                w1[0]=blo(rw.x); w1[1]=bhi(rw.x); w1[2]=blo(rw.y); w1[3]=bhi(rw.y);
                w1[4]=blo(rw.z); w1[5]=bhi(rw.z); w1[6]=blo(rw.w); w1[7]=bhi(rw.w);
            }
            {
                uint4 rw = *(const uint4*)(Wb + (size_t)(l + 128) * 106 + jj * 8);
                w2[0]=blo(rw.x); w2[1]=bhi(rw.x); w2[2]=blo(rw.y); w2[3]=bhi(rw.y);
                w2[4]=blo(rw.z); w2[5]=bhi(rw.z); w2[6]=blo(rw.w); w2[7]=bhi(rw.w);
            }
            #pragma unroll
            for (int k = 0; k < 9; ++k) {
                const __hip_bfloat16* dk = df + k * 192 + jj * 8;
                uint4 dA = *(const uint4*)(dk);        // c = 8jj..   (broadcast)
                uint4 dB = *(const uint4*)(dk + 96);   // c = 96+8jj.. (broadcast)
                uint4 dC;                              // a1 operand: lane-group select
                dC.x = hi2 ? dB.x : dA.x;
                dC.y = hi2 ? dB.y : dA.y;
                dC.z = hi2 ? dB.z : dA.z;
                dC.w = hi2 ? dB.w : dA.w;
                float fA[8], fB[8], fC[8];
                fA[0]=blo(dA.x); fA[1]=bhi(dA.x); fA[2]=blo(dA.y); fA[3]=bhi(dA.y);
                fA[4]=blo(dA.z); fA[5]=bhi(dA.z); fA[6]=blo(dA.w); fA[7]=bhi(dA.w);
                fB[0]=blo(dB.x); fB[1]=bhi(dB.x); fB[2]=blo(dB.y); fB[3]=bhi(dB.y);
                fB[4]=blo(dB.z); fB[5]=bhi(dB.z); fB[6]=blo(dB.w); fB[7]=bhi(dB.w);
                fC[0]=blo(dC.x); fC[1]=bhi(dC.x); fC[2]=blo(dC.y); fC[3]=bhi(dC.y);
                fC[4]=blo(dC.z); fC[5]=bhi(dC.z); fC[6]=blo(dC.w); fC[7]=bhi(dC.w);
                #pragma unroll
                for (int jr = 0; jr < 8; ++jr) {       // j = 8jj+jr ascending, chain order kept
                    a0[k] = fmaf(w0[jr], fA[jr], a0[k]);
                    a1[k] = fmaf(w1[jr], fC[jr], a1[k]);
                    a2[k] = fmaf(w2[jr], fB[jr], a2[k]);
                }
            }
        }
        float m0 = a0[0] + bo[0], m1 = a1[0] + bo[1], m2 = a2[0] + bo[2];
        #pragma unroll
        for (int k = 1; k < 9; ++k) {
            m0 = fmaxf(m0, a0[k] + bo[0]);
            m1 = fmaxf(m1, a1[k] + bo[1]);
            m2 = fmaxf(m2, a2[k] + bo[2]);
        }
        mx0[r] = fmaxf(m0, 0.f); mx1[r] = fmaxf(m1, 0.f); mx2[r] = fmaxf(m2, 0.f);
    }
    float* ob = out + ((size_t)b * OC_ + 192) * N_ + n0 + 4 * w;
    *(float4*)&ob[(size_t)(l)       * N_] = make_float4(mx0[0], mx0[1], mx0[2], mx0[3]);
    *(float4*)&ob[(size_t)(l + 64)  * N_] = make_float4(mx1[0], mx1[1], mx1[2], mx1[3]);
    *(float4*)&ob[(size_t)(l + 128) * N_] = make_float4(mx2[0], mx2[1], mx2[2], mx2[3]);
}

extern "C" void kernel_launch(void* const* d_in, const int* in_sizes, int n_in,
                              void* d_out, int out_size, void* d_ws, size_t ws_size,
                              hipStream_t stream) {
    (void)in_sizes; (void)n_in; (void)out_size; (void)ws_size;
    const float* x    = (const float*)d_in[0];
    const float* W    = (const float*)d_in[1];
    const float* bias = (const float*)d_in[2];
    float* out = (float*)d_out;

    _Float16* pHL = (_Float16*)d_ws;                       // 8*3136*384 f16 (hi|lo, node-major)
    float* xT   = (float*)(pHL + (size_t)B_ * N_ * 384);   // 8*3136*192 f32 raw
    float* sq   = xT + (size_t)B_ * N_ * C_;               // 8*3136 f32
    int*   nn   = (int*)(sq + (size_t)B_ * N_);            // 8*3136*9 i32
    float* pkv  = (float*)(nn + (size_t)B_ * N_ * K_);     // partial vals
    int*   pki  = (int*)(pkv + (size_t)B_ * QT_ * MS_ * 64 * 9);

    hipLaunchKernelGGL(prep_k,  dim3(98),   dim3(256), 0, stream, x, pHL, xT, sq);
    hipLaunchKernelGGL(knn_k,   dim3(B_ * QT_ * MS_), dim3(256), 0, stream, pHL, sq, pkv, pki);
    hipLaunchKernelGGL(merge_k, dim3(98),   dim3(256), 0, stream, pkv, pki, nn);
    hipLaunchKernelGGL(convi_k, dim3(392),  dim3(256), 0, stream, x, W, bias, out);
    hipLaunchKernelGGL(convd_k, dim3(1568), dim3(256), 0, stream, xT, nn, W, bias, out);
}

// Round 13
// 795.120 us; speedup vs baseline: 1.5156x; 1.2557x over previous
//
#include <hip/hip_runtime.h>
#include <hip/hip_bf16.h>
#include <cstdint>

#define B_ 8
#define C_ 192
#define N_ 3136
#define K_ 9
#define OC_ 384
#define QT_ 49            // q-tiles per batch (64 q each)
#define MS_ 4             // m-split over the 25 m-tiles (128 m each)
#define NT_ 25            // m-tiles
#define QSZ 24576         // Q region: 6 kc x 64 node x 64 f16 = 48KB

typedef unsigned int u32;
typedef _Float16 f16x8 __attribute__((ext_vector_type(8)));
typedef __fp16 h2 __attribute__((ext_vector_type(2)));
typedef float f32x4 __attribute__((ext_vector_type(4)));

#define GLD(g, s) __builtin_amdgcn_global_load_lds( \
    (const __attribute__((address_space(1))) void*)(g), \
    (__attribute__((address_space(3))) void*)(s), 16, 0, 0)

#define WAITV4 asm volatile("s_waitcnt vmcnt(4)" ::: "memory")
#define WAITV0 asm volatile("s_waitcnt vmcnt(0)" ::: "memory")

// if-converted sorted bubble insert (static indexing, strict < keeps earlier m)
#define INS(LV, LI, dd, mm) { \
    float cv = (dd); int ci = (mm); \
    _Pragma("unroll") \
    for (int r_ = 0; r_ < 9; ++r_) { \
        bool sw_ = cv < LV[r_]; \
        float tv_ = LV[r_]; int ti_ = LI[r_]; \
        LV[r_] = sw_ ? cv : tv_;  LI[r_] = sw_ ? ci : ti_; \
        cv = sw_ ? tv_ : cv;      ci = sw_ ? ti_ : ci; \
    } }

// ---------------- Kernel A: normalize + f16 hi/lo split + transpose + sq ----------------
// 64-thread blocks, grid 392: same per-thread arithmetic, spread over all CUs.
__global__ __launch_bounds__(64) void prep_k(const float* __restrict__ x,
                                             _Float16* __restrict__ pHL,
                                             float* __restrict__ xT,
                                             float* __restrict__ sq) {
    int g = blockIdx.x * 64 + threadIdx.x;       // 392*64 = 25088 exact
    int b = g / N_, n = g % N_;
    const float* xb = x + (size_t)b * C_ * N_ + n;
    float ss = 0.f;
    for (int c = 0; c < C_; ++c) { float v = xb[(size_t)c * N_]; ss = fmaf(v, v, ss); }
    float den = fmaxf(sqrtf(ss), 1e-12f);
    float* xrow = xT + (size_t)g * C_;
    _Float16* hrow = pHL + (size_t)g * 384;
    float s2 = 0.f;
    for (int c4 = 0; c4 < 48; ++c4) {
        float4 vv; float* pv = &vv.x;
        union { _Float16 f[4]; uint2 u; } uh, ul;
        #pragma unroll
        for (int j = 0; j < 4; ++j) {
            int c = 4 * c4 + j;
            float v = xb[(size_t)c * N_];
            float p = v / den;                    // IEEE div, matches np divide
            pv[j] = v;
            _Float16 h = (_Float16)p;            // rne
            uh.f[j] = h;
            ul.f[j] = (_Float16)(p - (float)h);  // residual
            s2 = fmaf(p, p, s2);                 // sq chain identical to passing rounds
        }
        *(float4*)&xrow[4 * c4] = vv;
        *(uint2*)&hrow[4 * c4] = uh.u;
        *(uint2*)&hrow[192 + 4 * c4] = ul.u;
    }
    sq[g] = s2;
}

// ---------------- Kernel B: MFMA distance GEMM (R10/R12, verbatim — frozen) ----------------
__global__ __launch_bounds__(256, 2) void knn_k(const _Float16* __restrict__ pHL,
                                                const float* __restrict__ sq,
                                                float* __restrict__ pkv,
                                                int* __restrict__ pki) {
    __shared__ _Float16 sh[40960];                // Q: 0..24575 | M0: +0 | M1: +8192
    float* dist = (float*)(sh + QSZ + 8192);      // aliases M1 (kc5 buf, dead at epilogue)
    const int tid = threadIdx.x;
    const int w = tid >> 6, l = tid & 63;
    const int lr = l & 15, lg = l >> 4;
    const int bid = blockIdx.x;
    const int b = bid & 7;                        // XCD-affinity: one batch per XCD
    const int r2_ = bid >> 3;                     // 0..195
    const int qt = r2_ >> 2, s4 = r2_ & 3;
    const int q0 = qt * 64;
    const char* hbB = (const char*)(pHL + (size_t)b * N_ * 384);
    const float* sqb = sq + b * N_;

    const int nl = l >> 3, sl = l & 7, ol = sl ^ nl;
    const size_t lane_src = (size_t)nl * 768 + (size_t)(ol >> 2) * 384 + (size_t)(ol & 3) * 16;
    const int slot_h = (lg ^ (lr & 7)) * 8;
    const int slot_l = ((4 | lg) ^ (lr & 7)) * 8;

    float sqq[4][4];
    #pragma unroll
    for (int qs = 0; qs < 4; ++qs)
        #pragma unroll
        for (int r = 0; r < 4; ++r) sqq[qs][r] = sqb[q0 + 16 * qs + 4 * lg + r];

    float lvA[9], lvB[9]; int liA[9], liB[9];
    #pragma unroll
    for (int r = 0; r < 9; ++r) {
        lvA[r] = INFINITY; liA[r] = 0x7fffffff;
        lvB[r] = INFINITY; liB[r] = 0x7fffffff;
    }

    auto stageM = [&](int mt_, int kc_, int buf) { // wave-local rows [32w, 32w+32)
        size_t mb = (size_t)(mt_ * 128 + w * 32) * 768 + (size_t)kc_ * 64;
        _Float16* md = sh + QSZ + buf * 8192 + w * 2048;
        #pragma unroll
        for (int i = 0; i < 4; ++i)
            GLD(hbB + mb + (size_t)i * 6144 + lane_src, md + i * 512);
    };

    #pragma unroll
    for (int kc = 0; kc < 6; ++kc) {
        size_t qb = (size_t)(q0 + w * 16) * 768 + (size_t)kc * 64;
        _Float16* qd = sh + kc * 4096 + w * 1024;
        GLD(hbB + qb + lane_src, qd);
        GLD(hbB + qb + 6144 + lane_src, qd + 512);
    }
    __syncthreads();                              // Q visible (drains vmem)
    stageM(s4, 0, 0);

    for (int mt = s4; mt < NT_; mt += MS_) {
        const int m0 = mt * 128;
        f32x4 acc[4][2];
        #pragma unroll
        for (int qs = 0; qs < 4; ++qs)
            #pragma unroll
            for (int ms = 0; ms < 2; ++ms) acc[qs][ms] = (f32x4)0.f;

        #pragma unroll
        for (int kc = 0; kc < 6; ++kc) {          // NO barriers in this loop
            const int nmt = (kc < 5) ? mt : mt + MS_;
            const int nkc = (kc < 5) ? kc + 1 : 0;
            if (nmt < NT_) {
                stageM(nmt, nkc, (kc + 1) & 1);
                WAITV4;
            } else {
                WAITV0;
            }
            const _Float16* Qb = sh + kc * 4096;
            const _Float16* Mb = sh + QSZ + (kc & 1) * 8192;
            f16x8 ah[4], al[4];
            #pragma unroll
            for (int qs = 0; qs < 4; ++qs) {
                const _Float16* qrow = Qb + (16 * qs + lr) * 64;
                ah[qs] = *(const f16x8*)(qrow + slot_h);
                al[qs] = *(const f16x8*)(qrow + slot_l);
            }
            #pragma unroll
            for (int ms = 0; ms < 2; ++ms) {
                const _Float16* mrow = Mb + (32 * w + 16 * ms + lr) * 64;
                f16x8 bh = *(const f16x8*)(mrow + slot_h);
                f16x8 bl = *(const f16x8*)(mrow + slot_l);
                #pragma unroll
                for (int qs = 0; qs < 4; ++qs) {
                    acc[qs][ms] = __builtin_amdgcn_mfma_f32_16x16x32_f16(al[qs], bh, acc[qs][ms], 0, 0, 0);
                    acc[qs][ms] = __builtin_amdgcn_mfma_f32_16x16x32_f16(ah[qs], bl, acc[qs][ms], 0, 0, 0);
                    acc[qs][ms] = __builtin_amdgcn_mfma_f32_16x16x32_f16(ah[qs], bh, acc[qs][ms], 0, 0, 0);
                }
            }
        }
        __syncthreads();                          // all waves done reading M bufs

        float sqm[2];
        #pragma unroll
        for (int ms = 0; ms < 2; ++ms) {
            int m = m0 + 32 * w + 16 * ms + lr;
            sqm[ms] = (m < N_) ? sqb[m] : 0.f;
        }
        #pragma unroll
        for (int pm = 0; pm < 2; ++pm) {
            if (m0 + 64 * pm >= N_) break;
            if ((w >> 1) == pm) {
                #pragma unroll
                for (int qs = 0; qs < 4; ++qs)
                    #pragma unroll
                    for (int ms = 0; ms < 2; ++ms) {
                        int col = 32 * (w & 1) + 16 * ms + lr;
                        int gsw = ((4 * qs + lg) ^ lr) << 2;
                        float4 v;
                        v.x = (sqq[qs][0] - 2.0f * acc[qs][ms][0]) + sqm[ms];
                        v.y = (sqq[qs][1] - 2.0f * acc[qs][ms][1]) + sqm[ms];
                        v.z = (sqq[qs][2] - 2.0f * acc[qs][ms][2]) + sqm[ms];
                        v.w = (sqq[qs][3] - 2.0f * acc[qs][ms][3]) + sqm[ms];
                        *(float4*)&dist[col * 64 + gsw] = v;
                    }
            }
            __syncthreads();
            const int gq = l >> 2, qe = l & 3;
            #pragma unroll
            for (int jj = 0; jj < 16; ++jj) {
                int col = 16 * w + jj;
                int m = m0 + 64 * pm + col;
                if (m < N_) {
                    float d = dist[col * 64 + ((gq ^ (col & 15)) << 2) + qe];
                    if (jj & 1) { INS(lvB, liB, d, m) }
                    else        { INS(lvA, liA, d, m) }
                }
            }
            __syncthreads();
        }
    }
    float* Lv = (float*)sh;
    int*   Li = (int*)sh + 4608;
    #pragma unroll
    for (int r = 0; r < 9; ++r) {
        Lv[(tid * 2 + 0) * 9 + r] = lvA[r]; Li[(tid * 2 + 0) * 9 + r] = liA[r];
        Lv[(tid * 2 + 1) * 9 + r] = lvB[r]; Li[(tid * 2 + 1) * 9 + r] = liB[r];
    }
    __syncthreads();
    if (tid < 64) {
        size_t base = ((size_t)((b * QT_ + qt) * MS_ + s4) * 64 + tid) * 9;
        for (int r = 0; r < K_; ++r) {
            float best = INFINITY; int bidx = 0x7fffffff; int bp = 0;
            for (int s = 0; s < 8; ++s) {
                int lb = (((s >> 1) * 64 + tid) * 2 + (s & 1)) * 9;
                for (int e = 0; e < 9; ++e) {
                    float v = Lv[lb + e]; int id = Li[lb + e];
                    if (v < best || (v == best && id < bidx)) { best = v; bidx = id; bp = lb + e; }
                }
            }
            pkv[base + r] = best;
            pki[base + r] = bidx;
            Lv[bp] = INFINITY;
        }
    }
}

// ---------------- Kernel B2: merge the 4 stride lists per query ----------------
__global__ __launch_bounds__(64) void merge_k(const float* __restrict__ pkv,
                                              const int* __restrict__ pki,
                                              int* __restrict__ nn) {
    int g = blockIdx.x * 64 + threadIdx.x;        // 392*64 = 25088 exact
    int b = g / N_, n = g % N_;
    int qt = n >> 6, q = n & 63;
    float v[MS_ * 9]; int id[MS_ * 9];
    #pragma unroll
    for (int s = 0; s < MS_; ++s) {
        size_t base = ((size_t)((b * QT_ + qt) * MS_ + s) * 64 + q) * 9;
        #pragma unroll
        for (int e = 0; e < 9; ++e) { v[s * 9 + e] = pkv[base + e]; id[s * 9 + e] = pki[base + e]; }
    }
    int* onn = nn + (size_t)g * K_;
    for (int r = 0; r < K_; ++r) {
        float best = INFINITY; int bidx = 0x7fffffff; int bp = 0;
        #pragma unroll
        for (int e = 0; e < MS_ * 9; ++e) {
            if (v[e] < best || (v[e] == best && id[e] < bidx)) { best = v[e]; bidx = id[e]; bp = e; }
        }
        onn[r] = bidx;
        v[bp] = INFINITY;
    }
}

// ---------------- Kernel C: channels 0..191, 8 oranges x 24 out-ch (grid 784) ----------------
__global__ __launch_bounds__(256) void convi_k(const float* __restrict__ x,
                                               const float* __restrict__ W,
                                               const float* __restrict__ bias,
                                               float* __restrict__ out) {
    __shared__ float Ws[24 * 96];
    const int orange = blockIdx.x & 7;
    const int nb = blockIdx.x >> 3;
    const int tid = threadIdx.x;
    const int g = nb * 256 + tid;
    const int b = g / N_, n = g % N_;
    const int o0 = orange * 24;
    const int cb = (o0 >= 96) ? 96 : 0;
    for (int i = 0; i < 9; ++i) {
        int e = tid + i * 256;
        Ws[e] = W[o0 * 96 + e];
    }
    __syncthreads();
    const float* xb = x + ((size_t)b * C_ + cb) * N_ + n;
    float xi[96];
    #pragma unroll
    for (int c = 0; c < 96; ++c) xi[c] = xb[(size_t)c * N_];
    float* ob = out + ((size_t)b * OC_ + o0) * N_ + n;
    for (int o = 0; o < 24; ++o) {
        float a = bias[o0 + o];
        #pragma unroll
        for (int c4 = 0; c4 < 24; ++c4) {
            float4 w4 = *(const float4*)&Ws[o * 96 + 4 * c4];
            a = fmaf(w4.x, xi[4*c4+0], a);
            a = fmaf(w4.y, xi[4*c4+1], a);
            a = fmaf(w4.z, xi[4*c4+2], a);
            a = fmaf(w4.w, xi[4*c4+3], a);
        }
        ob[(size_t)o * N_] = fmaxf(a, 0.f);
    }
}

// ---------------- Kernel D: channels 192..383 via v_dot2_f32_f16 ----------------
// dif + W stored as f16 (more mantissa than bf16); packed pairs feed fdot2
// directly -> no unpack VALU. Per-output pair order stays j-ascending.
__global__ __launch_bounds__(256) void convd_k(const float* __restrict__ xT,
                                               const int* __restrict__ nn,
                                               const float* __restrict__ W,
                                               const float* __restrict__ bias,
                                               float* __restrict__ out) {
    __shared__ _Float16 Wb[192 * 106];            // 40704 B
    __shared__ _Float16 dif[4][9 * 192];          // [wave][k][c], 13824 B
    const int tid = threadIdx.x;
    const int w = tid >> 6, l = tid & 63;
    const int b = blockIdx.x / 196;
    const int n0 = (blockIdx.x % 196) * 16;
    const bool hi2 = (l >= 32);                   // a1 group select

    for (int i = 0; i < 72; ++i) {
        int e = tid + i * 256;                    // 18432 = 192*96
        int row = e / 96, j = e % 96;
        Wb[row * 106 + j] = (_Float16)W[(192 + row) * 96 + j];
    }
    float bo[3];
    #pragma unroll
    for (int oi = 0; oi < 3; ++oi) bo[oi] = bias[192 + l + 64 * oi];
    __syncthreads();

    _Float16* df = dif[w];
    const float* xTb = xT + (size_t)b * N_ * C_;
    float mx0[4], mx1[4], mx2[4];

    #pragma unroll
    for (int r = 0; r < 4; ++r) {
        const int n = n0 + 4 * w + r;
        const float* xin = xTb + (size_t)n * C_;
        float xi0 = xin[l], xi1 = xin[l + 64], xi2 = xin[l + 128];
        const int* nb2 = nn + ((size_t)b * N_ + n) * K_;
        __syncthreads();                          // WAR vs previous round's reads
        #pragma unroll
        for (int k = 0; k < K_; ++k) {
            int idx = nb2[k];
            const float* xj = xTb + (size_t)idx * C_;
            df[k * 192 + l]       = (_Float16)(xj[l]       - xi0);
            df[k * 192 + l + 64]  = (_Float16)(xj[l + 64]  - xi1);
            df[k * 192 + l + 128] = (_Float16)(xj[l + 128] - xi2);
        }
        __syncthreads();                          // writes visible
        float a0[9], a1[9], a2[9];
        #pragma unroll
        for (int k = 0; k < 9; ++k) { a0[k] = 0.f; a1[k] = 0.f; a2[k] = 0.f; }

        for (int jj = 0; jj < 12; ++jj) {
            union U { uint4 u; h2 p[4]; };
            U w0u, w1u, w2u;
            w0u.u = *(const uint4*)(Wb + (size_t)l * 106 + jj * 8);
            w1u.u = *(const uint4*)(Wb + (size_t)(l + 64) * 106 + jj * 8);
            w2u.u = *(const uint4*)(Wb + (size_t)(l + 128) * 106 + jj * 8);
            #pragma unroll
            for (int k = 0; k < 9; ++k) {
                const _Float16* dk = df + k * 192 + jj * 8;
                U dA, dB, dC;
                dA.u = *(const uint4*)(dk);            // c = 8jj..    (broadcast)
                dB.u = *(const uint4*)(dk + 96);       // c = 96+8jj.. (broadcast)
                dC.u.x = hi2 ? dB.u.x : dA.u.x;        // a1 operand: lane-group select
                dC.u.y = hi2 ? dB.u.y : dA.u.y;
                dC.u.z = hi2 ? dB.u.z : dA.u.z;
                dC.u.w = hi2 ? dB.u.w : dA.u.w;
                #pragma unroll
                for (int p = 0; p < 4; ++p) {          // pairs j-ascending
                    a0[k] = __builtin_amdgcn_fdot2(w0u.p[p], dA.p[p], a0[k], false);
                    a1[k] = __builtin_amdgcn_fdot2(w1u.p[p], dC.p[p], a1[k], false);
                    a2[k] = __builtin_amdgcn_fdot2(w2u.p[p], dB.p[p], a2[k], false);
                }
            }
        }
        float m0 = a0[0] + bo[0], m1 = a1[0] + bo[1], m2 = a2[0] + bo[2];
        #pragma unroll
        for (int k = 1; k < 9; ++k) {
            m0 = fmaxf(m0, a0[k] + bo[0]);
            m1 = fmaxf(m1, a1[k] + bo[1]);
            m2 = fmaxf(m2, a2[k] + bo[2]);
        }
        mx0[r] = fmaxf(m0, 0.f); mx1[r] = fmaxf(m1, 0.f); mx2[r] = fmaxf(m2, 0.f);
    }
    float* ob = out + ((size_t)b * OC_ + 192) * N_ + n0 + 4 * w;
    *(float4*)&ob[(size_t)(l)       * N_] = make_float4(mx0[0], mx0[1], mx0[2], mx0[3]);
    *(float4*)&ob[(size_t)(l + 64)  * N_] = make_float4(mx1[0], mx1[1], mx1[2], mx1[3]);
    *(float4*)&ob[(size_t)(l + 128) * N_] = make_float4(mx2[0], mx2[1], mx2[2], mx2[3]);
}

extern "C" void kernel_launch(void* const* d_in, const int* in_sizes, int n_in,
                              void* d_out, int out_size, void* d_ws, size_t ws_size,
                              hipStream_t stream) {
    (void)in_sizes; (void)n_in; (void)out_size; (void)ws_size;
    const float* x    = (const float*)d_in[0];
    const float* W    = (const float*)d_in[1];
    const float* bias = (const float*)d_in[2];
    float* out = (float*)d_out;

    _Float16* pHL = (_Float16*)d_ws;                       // 8*3136*384 f16 (hi|lo, node-major)
    float* xT   = (float*)(pHL + (size_t)B_ * N_ * 384);   // 8*3136*192 f32 raw
    float* sq   = xT + (size_t)B_ * N_ * C_;               // 8*3136 f32
    int*   nn   = (int*)(sq + (size_t)B_ * N_);            // 8*3136*9 i32
    float* pkv  = (float*)(nn + (size_t)B_ * N_ * K_);     // partial vals
    int*   pki  = (int*)(pkv + (size_t)B_ * QT_ * MS_ * 64 * 9);

    hipLaunchKernelGGL(prep_k,  dim3(392),  dim3(64),  0, stream, x, pHL, xT, sq);
    hipLaunchKernelGGL(knn_k,   dim3(B_ * QT_ * MS_), dim3(256), 0, stream, pHL, sq, pkv, pki);
    hipLaunchKernelGGL(merge_k, dim3(392),  dim3(64),  0, stream, pkv, pki, nn);
    hipLaunchKernelGGL(convi_k, dim3(784),  dim3(256), 0, stream, x, W, bias, out);
    hipLaunchKernelGGL(convd_k, dim3(1568), dim3(256), 0, stream, xT, nn, W, bias, out);
}

// Round 14
// 673.888 us; speedup vs baseline: 1.7883x; 1.1799x over previous
//
#include <hip/hip_runtime.h>
#include <hip/hip_bf16.h>
#include <cstdint>

#define B_ 8
#define C_ 192
#define N_ 3136
#define K_ 9
#define OC_ 384
#define QT_ 49            // q-tiles per batch (64 q each)
#define MS_ 4             // m-split stride over the 49 m-tiles (64 m each)
#define NT_ 49            // m-tiles (3136/64 exact, no tail)
#define QSZ 24576         // Q region: 6 kc x 64 node x 64 f16 = 48KB

typedef unsigned int u32;
typedef _Float16 f16x8 __attribute__((ext_vector_type(8)));
typedef __fp16 h2 __attribute__((ext_vector_type(2)));
typedef float f32x4 __attribute__((ext_vector_type(4)));

#define GLD(g, s) __builtin_amdgcn_global_load_lds( \
    (const __attribute__((address_space(1))) void*)(g), \
    (__attribute__((address_space(3))) void*)(s), 16, 0, 0)

#define WAITV2 asm volatile("s_waitcnt vmcnt(2)" ::: "memory")
#define WAITV0 asm volatile("s_waitcnt vmcnt(0)" ::: "memory")

// if-converted sorted bubble insert (static indexing, strict < keeps earlier m)
#define INS(LV, LI, dd, mm) { \
    float cv = (dd); int ci = (mm); \
    _Pragma("unroll") \
    for (int r_ = 0; r_ < 9; ++r_) { \
        bool sw_ = cv < LV[r_]; \
        float tv_ = LV[r_]; int ti_ = LI[r_]; \
        LV[r_] = sw_ ? cv : tv_;  LI[r_] = sw_ ? ci : ti_; \
        cv = sw_ ? tv_ : cv;      ci = sw_ ? ti_ : ci; \
    } }

// ---------------- Kernel A: normalize + f16 hi/lo split + transpose + sq ----------------
__global__ __launch_bounds__(64) void prep_k(const float* __restrict__ x,
                                             _Float16* __restrict__ pHL,
                                             float* __restrict__ xT,
                                             float* __restrict__ sq) {
    int g = blockIdx.x * 64 + threadIdx.x;       // 392*64 = 25088 exact
    int b = g / N_, n = g % N_;
    const float* xb = x + (size_t)b * C_ * N_ + n;
    float ss = 0.f;
    for (int c = 0; c < C_; ++c) { float v = xb[(size_t)c * N_]; ss = fmaf(v, v, ss); }
    float den = fmaxf(sqrtf(ss), 1e-12f);
    float* xrow = xT + (size_t)g * C_;
    _Float16* hrow = pHL + (size_t)g * 384;
    float s2 = 0.f;
    for (int c4 = 0; c4 < 48; ++c4) {
        float4 vv; float* pv = &vv.x;
        union { _Float16 f[4]; uint2 u; } uh, ul;
        #pragma unroll
        for (int j = 0; j < 4; ++j) {
            int c = 4 * c4 + j;
            float v = xb[(size_t)c * N_];
            float p = v / den;                    // IEEE div, matches np divide
            pv[j] = v;
            _Float16 h = (_Float16)p;            // rne
            uh.f[j] = h;
            ul.f[j] = (_Float16)(p - (float)h);  // residual
            s2 = fmaf(p, p, s2);                 // sq chain identical to passing rounds
        }
        *(float4*)&xrow[4 * c4] = vv;
        *(uint2*)&hrow[4 * c4] = uh.u;
        *(uint2*)&hrow[192 + 4 * c4] = ul.u;
    }
    sq[g] = s2;
}

// ---------------- Kernel B: MFMA distance GEMM, 64KB LDS -> true 2 blocks/CU ----------------
// Block 64q x 64m-tile, 4 waves; wave tile 64q x 16m (4 mfma tiles x 3 products).
// Q resident 48KB; M dbuf 2x8KB wave-local (rows [16w,16w+16), 2 GLD/kc, WAITV2,
// no barriers in kc-loop). 49 m-tiles cover N exactly (no tail guards).
__global__ __launch_bounds__(256, 2) void knn_k(const _Float16* __restrict__ pHL,
                                                const float* __restrict__ sq,
                                                float* __restrict__ pkv,
                                                int* __restrict__ pki) {
    __shared__ _Float16 sh[32768];                // 64KB: Q 0..24575 | M0 +0 | M1 +4096
    float* dist = (float*)(sh + QSZ);             // 16KB, aliases M0+M1 (dead at epilogue)
    const int tid = threadIdx.x;
    const int w = tid >> 6, l = tid & 63;
    const int lr = l & 15, lg = l >> 4;
    const int bid = blockIdx.x;
    const int b = bid & 7;                        // XCD-affinity: one batch per XCD
    const int r2_ = bid >> 3;                     // 0..195
    const int qt = r2_ >> 2, s4 = r2_ & 3;
    const int q0 = qt * 64;
    const char* hbB = (const char*)(pHL + (size_t)b * N_ * 384);
    const float* sqb = sq + b * N_;

    const int nl = l >> 3, sl = l & 7, ol = sl ^ nl;
    const size_t lane_src = (size_t)nl * 768 + (size_t)(ol >> 2) * 384 + (size_t)(ol & 3) * 16;
    const int slot_h = (lg ^ (lr & 7)) * 8;
    const int slot_l = ((4 | lg) ^ (lr & 7)) * 8;

    float sqq[4][4];
    #pragma unroll
    for (int qs = 0; qs < 4; ++qs)
        #pragma unroll
        for (int r = 0; r < 4; ++r) sqq[qs][r] = sqb[q0 + 16 * qs + 4 * lg + r];

    float lvA[9], lvB[9]; int liA[9], liB[9];
    #pragma unroll
    for (int r = 0; r < 9; ++r) {
        lvA[r] = INFINITY; liA[r] = 0x7fffffff;
        lvB[r] = INFINITY; liB[r] = 0x7fffffff;
    }

    auto stageM = [&](int mt_, int kc_, int buf) { // wave-local rows [16w, 16w+16)
        size_t mb = (size_t)(mt_ * 64 + w * 16) * 768 + (size_t)kc_ * 64;
        _Float16* md = sh + QSZ + buf * 4096 + w * 1024;
        GLD(hbB + mb + lane_src, md);
        GLD(hbB + mb + 6144 + lane_src, md + 512);
    };

    // ---- stage Q once: [6 kc][64 node][64 f16]; wave w rows [16w,16w+16) ----
    #pragma unroll
    for (int kc = 0; kc < 6; ++kc) {
        size_t qb = (size_t)(q0 + w * 16) * 768 + (size_t)kc * 64;
        _Float16* qd = sh + kc * 4096 + w * 1024;
        GLD(hbB + qb + lane_src, qd);
        GLD(hbB + qb + 6144 + lane_src, qd + 512);
    }
    __syncthreads();                              // Q visible (drains vmem)

    for (int mt = s4; mt < NT_; mt += MS_) {
        const int m0 = mt * 64;
        stageM(mt, 0, 0);                         // tile-start stage (exposed ~1 L2 trip)
        f32x4 acc[4];
        #pragma unroll
        for (int qs = 0; qs < 4; ++qs) acc[qs] = (f32x4)0.f;

        #pragma unroll
        for (int kc = 0; kc < 6; ++kc) {          // NO barriers in this loop
            if (kc < 5) {
                stageM(mt, kc + 1, (kc + 1) & 1); // issue next chunk
                WAITV2;                           // oldest 2 = stage(kc) complete
            } else {
                WAITV0;
            }
            const _Float16* Qb = sh + kc * 4096;
            const _Float16* mrow = sh + QSZ + (kc & 1) * 4096 + (16 * w + lr) * 64;
            f16x8 bh = *(const f16x8*)(mrow + slot_h);
            f16x8 bl = *(const f16x8*)(mrow + slot_l);
            #pragma unroll
            for (int qs = 0; qs < 4; ++qs) {
                const _Float16* qrow = Qb + (16 * qs + lr) * 64;
                f16x8 ah = *(const f16x8*)(qrow + slot_h);
                f16x8 al = *(const f16x8*)(qrow + slot_l);
                acc[qs] = __builtin_amdgcn_mfma_f32_16x16x32_f16(al, bh, acc[qs], 0, 0, 0);
                acc[qs] = __builtin_amdgcn_mfma_f32_16x16x32_f16(ah, bl, acc[qs], 0, 0, 0);
                acc[qs] = __builtin_amdgcn_mfma_f32_16x16x32_f16(ah, bh, acc[qs], 0, 0, 0);
            }
        }
        __syncthreads();                          // all waves done reading M bufs

        // ---- epilogue: dist[64 m][64 q] (16KB) ----
        const float sqm = sqb[m0 + 16 * w + lr];
        {
            const int col = 16 * w + lr;
            #pragma unroll
            for (int qs = 0; qs < 4; ++qs) {
                int gsw = ((4 * qs + lg) ^ lr) << 2;   // XOR-granule swizzle
                float4 v;
                v.x = (sqq[qs][0] - 2.0f * acc[qs][0]) + sqm;
                v.y = (sqq[qs][1] - 2.0f * acc[qs][1]) + sqm;
                v.z = (sqq[qs][2] - 2.0f * acc[qs][2]) + sqm;
                v.w = (sqq[qs][3] - 2.0f * acc[qs][3]) + sqm;
                *(float4*)&dist[col * 64 + gsw] = v;
            }
        }
        __syncthreads();
        // ---- scan: query = l (qs_), wave w owns cols [16w,16w+16) ----
        const int gq = l >> 2, qe = l & 3;
        #pragma unroll
        for (int jj = 0; jj < 16; ++jj) {
            int col = 16 * w + jj;
            int m = m0 + col;                     // always < N_ (49*64 = 3136 exact)
            float d = dist[col * 64 + ((gq ^ (col & 15)) << 2) + qe];
            if (jj & 1) { INS(lvB, liB, d, m) }
            else        { INS(lvA, liA, d, m) }
        }
        __syncthreads();                          // scans done before next tile's stage
    }
    // ---- merge the 8 lists per query (stable: val asc, idx asc) ----
    float* Lv = (float*)sh;
    int*   Li = (int*)sh + 4608;
    #pragma unroll
    for (int r = 0; r < 9; ++r) {
        Lv[(tid * 2 + 0) * 9 + r] = lvA[r]; Li[(tid * 2 + 0) * 9 + r] = liA[r];
        Lv[(tid * 2 + 1) * 9 + r] = lvB[r]; Li[(tid * 2 + 1) * 9 + r] = liB[r];
    }
    __syncthreads();
    if (tid < 64) {
        size_t base = ((size_t)((b * QT_ + qt) * MS_ + s4) * 64 + tid) * 9;
        for (int r = 0; r < K_; ++r) {
            float best = INFINITY; int bidx = 0x7fffffff; int bp = 0;
            for (int s = 0; s < 8; ++s) {
                int lb = (((s >> 1) * 64 + tid) * 2 + (s & 1)) * 9;
                for (int e = 0; e < 9; ++e) {
                    float v = Lv[lb + e]; int id = Li[lb + e];
                    if (v < best || (v == best && id < bidx)) { best = v; bidx = id; bp = lb + e; }
                }
            }
            pkv[base + r] = best;
            pki[base + r] = bidx;
            Lv[bp] = INFINITY;
        }
    }
}

// ---------------- Kernel B2: merge the 4 stride lists per query ----------------
__global__ __launch_bounds__(64) void merge_k(const float* __restrict__ pkv,
                                              const int* __restrict__ pki,
                                              int* __restrict__ nn) {
    int g = blockIdx.x * 64 + threadIdx.x;        // 392*64 = 25088 exact
    int b = g / N_, n = g % N_;
    int qt = n >> 6, q = n & 63;
    float v[MS_ * 9]; int id[MS_ * 9];
    #pragma unroll
    for (int s = 0; s < MS_; ++s) {
        size_t base = ((size_t)((b * QT_ + qt) * MS_ + s) * 64 + q) * 9;
        #pragma unroll
        for (int e = 0; e < 9; ++e) { v[s * 9 + e] = pkv[base + e]; id[s * 9 + e] = pki[base + e]; }
    }
    int* onn = nn + (size_t)g * K_;
    for (int r = 0; r < K_; ++r) {
        float best = INFINITY; int bidx = 0x7fffffff; int bp = 0;
        #pragma unroll
        for (int e = 0; e < MS_ * 9; ++e) {
            if (v[e] < best || (v[e] == best && id[e] < bidx)) { best = v[e]; bidx = id[e]; bp = e; }
        }
        onn[r] = bidx;
        v[bp] = INFINITY;
    }
}

// ---------------- Kernel C: channels 0..191, 8 oranges x 24 out-ch (grid 784) ----------------
__global__ __launch_bounds__(256) void convi_k(const float* __restrict__ x,
                                               const float* __restrict__ W,
                                               const float* __restrict__ bias,
                                               float* __restrict__ out) {
    __shared__ float Ws[24 * 96];
    const int orange = blockIdx.x & 7;
    const int nb = blockIdx.x >> 3;
    const int tid = threadIdx.x;
    const int g = nb * 256 + tid;
    const int b = g / N_, n = g % N_;
    const int o0 = orange * 24;
    const int cb = (o0 >= 96) ? 96 : 0;
    for (int i = 0; i < 9; ++i) {
        int e = tid + i * 256;
        Ws[e] = W[o0 * 96 + e];
    }
    __syncthreads();
    const float* xb = x + ((size_t)b * C_ + cb) * N_ + n;
    float xi[96];
    #pragma unroll
    for (int c = 0; c < 96; ++c) xi[c] = xb[(size_t)c * N_];
    float* ob = out + ((size_t)b * OC_ + o0) * N_ + n;
    for (int o = 0; o < 24; ++o) {
        float a = bias[o0 + o];
        #pragma unroll
        for (int c4 = 0; c4 < 24; ++c4) {
            float4 w4 = *(const float4*)&Ws[o * 96 + 4 * c4];
            a = fmaf(w4.x, xi[4*c4+0], a);
            a = fmaf(w4.y, xi[4*c4+1], a);
            a = fmaf(w4.z, xi[4*c4+2], a);
            a = fmaf(w4.w, xi[4*c4+3], a);
        }
        ob[(size_t)o * N_] = fmaxf(a, 0.f);
    }
}

// ---------------- Kernel D: channels 192..383 via v_dot2_f32_f16 ----------------
__global__ __launch_bounds__(256) void convd_k(const float* __restrict__ xT,
                                               const int* __restrict__ nn,
                                               const float* __restrict__ W,
                                               const float* __restrict__ bias,
                                               float* __restrict__ out) {
    __shared__ _Float16 Wb[192 * 106];            // 40704 B
    __shared__ _Float16 dif[4][9 * 192];          // [wave][k][c], 13824 B
    const int tid = threadIdx.x;
    const int w = tid >> 6, l = tid & 63;
    const int b = blockIdx.x / 196;
    const int n0 = (blockIdx.x % 196) * 16;
    const bool hi2 = (l >= 32);                   // a1 group select

    for (int i = 0; i < 72; ++i) {
        int e = tid + i * 256;                    // 18432 = 192*96
        int row = e / 96, j = e % 96;
        Wb[row * 106 + j] = (_Float16)W[(192 + row) * 96 + j];
    }
    float bo[3];
    #pragma unroll
    for (int oi = 0; oi < 3; ++oi) bo[oi] = bias[192 + l + 64 * oi];
    __syncthreads();

    _Float16* df = dif[w];
    const float* xTb = xT + (size_t)b * N_ * C_;
    float mx0[4], mx1[4], mx2[4];

    #pragma unroll
    for (int r = 0; r < 4; ++r) {
        const int n = n0 + 4 * w + r;
        const float* xin = xTb + (size_t)n * C_;
        float xi0 = xin[l], xi1 = xin[l + 64], xi2 = xin[l + 128];
        const int* nb2 = nn + ((size_t)b * N_ + n) * K_;
        __syncthreads();                          // WAR vs previous round's reads
        #pragma unroll
        for (int k = 0; k < K_; ++k) {
            int idx = nb2[k];
            const float* xj = xTb + (size_t)idx * C_;
            df[k * 192 + l]       = (_Float16)(xj[l]       - xi0);
            df[k * 192 + l + 64]  = (_Float16)(xj[l + 64]  - xi1);
            df[k * 192 + l + 128] = (_Float16)(xj[l + 128] - xi2);
        }
        __syncthreads();                          // writes visible
        float a0[9], a1[9], a2[9];
        #pragma unroll
        for (int k = 0; k < 9; ++k) { a0[k] = 0.f; a1[k] = 0.f; a2[k] = 0.f; }

        for (int jj = 0; jj < 12; ++jj) {
            union U { uint4 u; h2 p[4]; };
            U w0u, w1u, w2u;
            w0u.u = *(const uint4*)(Wb + (size_t)l * 106 + jj * 8);
            w1u.u = *(const uint4*)(Wb + (size_t)(l + 64) * 106 + jj * 8);
            w2u.u = *(const uint4*)(Wb + (size_t)(l + 128) * 106 + jj * 8);
            #pragma unroll
            for (int k = 0; k < 9; ++k) {
                const _Float16* dk = df + k * 192 + jj * 8;
                U dA, dB, dC;
                dA.u = *(const uint4*)(dk);            // c = 8jj..    (broadcast)
                dB.u = *(const uint4*)(dk + 96);       // c = 96+8jj.. (broadcast)
                dC.u.x = hi2 ? dB.u.x : dA.u.x;        // a1 operand: lane-group select
                dC.u.y = hi2 ? dB.u.y : dA.u.y;
                dC.u.z = hi2 ? dB.u.z : dA.u.z;
                dC.u.w = hi2 ? dB.u.w : dA.u.w;
                #pragma unroll
                for (int p = 0; p < 4; ++p) {          // pairs j-ascending
                    a0[k] = __builtin_amdgcn_fdot2(w0u.p[p], dA.p[p], a0[k], false);
                    a1[k] = __builtin_amdgcn_fdot2(w1u.p[p], dC.p[p], a1[k], false);
                    a2[k] = __builtin_amdgcn_fdot2(w2u.p[p], dB.p[p], a2[k], false);
                }
            }
        }
        float m0 = a0[0] + bo[0], m1 = a1[0] + bo[1], m2 = a2[0] + bo[2];
        #pragma unroll
        for (int k = 1; k < 9; ++k) {
            m0 = fmaxf(m0, a0[k] + bo[0]);
            m1 = fmaxf(m1, a1[k] + bo[1]);
            m2 = fmaxf(m2, a2[k] + bo[2]);
        }
        mx0[r] = fmaxf(m0, 0.f); mx1[r] = fmaxf(m1, 0.f); mx2[r] = fmaxf(m2, 0.f);
    }
    float* ob = out + ((size_t)b * OC_ + 192) * N_ + n0 + 4 * w;
    *(float4*)&ob[(size_t)(l)       * N_] = make_float4(mx0[0], mx0[1], mx0[2], mx0[3]);
    *(float4*)&ob[(size_t)(l + 64)  * N_] = make_float4(mx1[0], mx1[1], mx1[2], mx1[3]);
    *(float4*)&ob[(size_t)(l + 128) * N_] = make_float4(mx2[0], mx2[1], mx2[2], mx2[3]);
}

extern "C" void kernel_launch(void* const* d_in, const int* in_sizes, int n_in,
                              void* d_out, int out_size, void* d_ws, size_t ws_size,
                              hipStream_t stream) {
    (void)in_sizes; (void)n_in; (void)out_size; (void)ws_size;
    const float* x    = (const float*)d_in[0];
    const float* W    = (const float*)d_in[1];
    const float* bias = (const float*)d_in[2];
    float* out = (float*)d_out;

    _Float16* pHL = (_Float16*)d_ws;                       // 8*3136*384 f16 (hi|lo, node-major)
    float* xT   = (float*)(pHL + (size_t)B_ * N_ * 384);   // 8*3136*192 f32 raw
    float* sq   = xT + (size_t)B_ * N_ * C_;               // 8*3136 f32
    int*   nn   = (int*)(sq + (size_t)B_ * N_);            // 8*3136*9 i32
    float* pkv  = (float*)(nn + (size_t)B_ * N_ * K_);     // partial vals
    int*   pki  = (int*)(pkv + (size_t)B_ * QT_ * MS_ * 64 * 9);

    hipLaunchKernelGGL(prep_k,  dim3(392),  dim3(64),  0, stream, x, pHL, xT, sq);
    hipLaunchKernelGGL(knn_k,   dim3(B_ * QT_ * MS_), dim3(256), 0, stream, pHL, sq, pkv, pki);
    hipLaunchKernelGGL(merge_k, dim3(392),  dim3(64),  0, stream, pkv, pki, nn);
    hipLaunchKernelGGL(convi_k, dim3(784),  dim3(256), 0, stream, x, W, bias, out);
    hipLaunchKernelGGL(convd_k, dim3(1568), dim3(256), 0, stream, xT, nn, W, bias, out);
}